// Round 3
// baseline (331.441 us; speedup 1.0000x reference)
//
#include <hip/hip_runtime.h>
#include <math.h>

// ---------------------------------------------------------------------------
// LinearAttention, folded. Plain dispatches only (no cooperative launch).
//   cvt/trans/wq: x->bf16, Wkv^T->bf16, Wq*scale->bf16
//   gemm1: kv = x @ Wkv  (256^2 8-phase MFMA, reg-dbuf frags, XCD-swizzled)
//   ctx:   ctx[b,h,d,e] = sum_n_unmasked exp(k)*v ; sumexp folded (pre-mask)
//   m2:    M2t[b] = (blockdiag(ctx)/sumexp @ Wout)^T  bf16
//   m3:    M3t[b] = M2t[b] @ (s*Wq)^T                 bf16  (m97 structure)
//   gemm2: out = x @ M3t^T + b_out (fp32, same 8-phase core, XCD-swizzled)
// B=4 T=4096 DIM=1024 H=16 Dh=64.
//
// Round-3: register-double-buffered fragments in the 8-phase core.
// Phase P: [vmcnt(4) odd phases] -> stage 1 unit -> ds_read frags for P+1
// into other reg bank -> lgkmcnt(4|8) (leaves P+1 reads pending under MFMA)
// + sched_barrier(0) -> setprio(1) 16xMFMA setprio(0) -> ONE s_barrier.
// LDS read pipe now overlaps the MFMA window (round-2 serialized them:
// MfmaUtil 34%, phase 1560cyc vs 620 MFMA + ~500 LDS content).
// Wait schedule re-derived: unit staged 4 phases before vmcnt-forced land;
// frag reads lgkm-complete before the phase-end barrier, overwrites >=2
// barriers later. Epilogue: ph1/2 staging kept (t15 KS1), vmcnt(0) at ph5.
// ---------------------------------------------------------------------------

typedef __bf16 bf16;
typedef __attribute__((ext_vector_type(4))) float f32x4;
typedef __attribute__((ext_vector_type(8))) __bf16 bf16x8;
typedef __attribute__((ext_vector_type(4))) __bf16 bf16x4;

#define SCALE_ 0.125f   // 64^-0.5

__device__ __forceinline__ void g2l16(const void* g, void* l) {
  __builtin_amdgcn_global_load_lds((const __attribute__((address_space(1))) void*)g,
                                   (__attribute__((address_space(3))) void*)l, 16, 0, 0);
}

// ---- x (fp32) -> bf16, vectorized (round-2 verified) ----------------------
__global__ __launch_bounds__(256) void k_cvt(const float* __restrict__ in,
                                             bf16* __restrict__ out, int n4) {
  int i = blockIdx.x * 256 + threadIdx.x;
  if (i >= n4) return;
  f32x4 v = ((const f32x4*)in)[i];
  bf16x4 o;
  o[0] = (bf16)v[0]; o[1] = (bf16)v[1]; o[2] = (bf16)v[2]; o[3] = (bf16)v[3];
  ((bf16x4*)out)[i] = o;
}

// ---- W_qkv[:,1024:3072] fp32 -> wt [2048][1024] bf16 (round-2 verified) ---
__global__ __launch_bounds__(256) void k_trans(const float* __restrict__ W,
                                               bf16* __restrict__ Wt) {
  __shared__ float t[32][33];
  int n0 = blockIdx.x * 32, k0 = blockIdx.y * 32;
  int tx = threadIdx.x & 31, ty = threadIdx.x >> 5;
  #pragma unroll
  for (int s = 0; s < 4; s++) {
    int k = ty + s * 8;
    t[k][tx] = W[(size_t)(k0 + k) * 3072 + 1024 + n0 + tx];
  }
  __syncthreads();
  #pragma unroll
  for (int s = 0; s < 4; s++) {
    int n = ty + s * 8;
    Wt[(size_t)(n0 + n) * 1024 + k0 + tx] = (bf16)t[tx][n];
  }
}

// ---- wqs[i][d] = scale * Wqkv[i][d] (round-2 verified) --------------------
__global__ __launch_bounds__(256) void k_wq(const float* __restrict__ W,
                                            bf16* __restrict__ wqs) {
  int idx = blockIdx.x * 256 + threadIdx.x;     // 1024*256 total
  int i = idx >> 8, d4 = idx & 255;
  f32x4 v = *(const f32x4*)(W + (size_t)i * 3072 + d4 * 4);
  bf16x4 o;
  o[0] = (bf16)(v[0] * SCALE_); o[1] = (bf16)(v[1] * SCALE_);
  o[2] = (bf16)(v[2] * SCALE_); o[3] = (bf16)(v[3] * SCALE_);
  *(bf16x4*)(wqs + (size_t)i * 1024 + d4 * 4) = o;
}

// ===========================================================================
// 256x256 / BK=64 / 8-wave / 8-phase GEMM core, reg-dbuf frags (K = 1024)
// LDS map (bytes): buf d at d*65536; within buf: A-ks0 +0, A-ks1 +16384,
//                  B-ks0 +32768, B-ks1 +49152. Unit = 16KB K-half.
// ===========================================================================

__device__ __forceinline__ void stage_unit(const bf16* __restrict__ G, int base_row,
                                           int kcol, void* ldsBase, int tid) {
  #pragma unroll
  for (int r = 0; r < 2; ++r) {
    const int d  = tid * 16 + r * 8192;              // linear byte in unit
    const int lb = d ^ (((d >> 7) & 3) << 4);        // logical byte (involution)
    g2l16(G + (size_t)(base_row + (lb >> 6)) * 1024 + kcol + ((lb & 63) >> 1),
          (char*)ldsBase + d);
  }
}

#define VM(n) asm volatile("s_waitcnt vmcnt(" #n ")" ::: "memory")
#define LG(n) do { asm volatile("s_waitcnt lgkmcnt(" #n ")" ::: "memory"); \
                   __builtin_amdgcn_sched_barrier(0); } while (0)

#define DSA(bank, DB, MH, KS)                                                 \
  { const char* p_ = Lraw + (DB) * 65536 + (KS) * 16384;                      \
    _Pragma("unroll") for (int i_ = 0; i_ < 4; ++i_)                          \
      bank[i_] = *(const bf16x8*)(p_ + aoff[MH][i_]); }
#define DSB(bank, DB, KS)                                                     \
  { const char* p_ = Lraw + (DB) * 65536 + 32768 + (KS) * 16384;              \
    _Pragma("unroll") for (int j_ = 0; j_ < 4; ++j_)                          \
      bank[j_] = *(const bf16x8*)(p_ + boff[j_]); }

#define MFMA16(AF, BF, MH)                                                    \
  __builtin_amdgcn_s_setprio(1);                                              \
  _Pragma("unroll") for (int i_ = 0; i_ < 4; ++i_)                            \
    _Pragma("unroll") for (int j_ = 0; j_ < 4; ++j_)                          \
      acc[(MH) * 4 + i_][j_] = __builtin_amdgcn_mfma_f32_16x16x32_bf16(       \
          AF[i_], BF[j_], acc[(MH) * 4 + i_][j_], 0, 0, 0);                   \
  __builtin_amdgcn_s_setprio(0)

#define BAR() __builtin_amdgcn_s_barrier()

// One iteration = tiles (2I: buf0, ph1-4) and (2I+1: buf1, ph5-8).
// Staging: ph1 A1(2I+1), ph2 B1(2I+1), ph3 A0(2I+2), ph4 B0(2I+2),
//          ph5 A1(2I+2), ph6 B1(2I+2), ph7 A0(2I+3), ph8 B0(2I+3).
// PF=0 (epilogue, tiles 14/15): keep ph1/2 staging, drop ph3-8, ph5 vm(0).
#define GITER(PF, KB)                                                         \
  /* ph1: MFMA(af_a,bf_a,MH0) buf0  | issue af_b<-ph2 */                      \
  VM(4);                                                                      \
  stage_unit(A_, row0, (KB) + 96, Lraw + 65536 + 16384, tid);                 \
  DSA(af_b, 0, 1, 0);                                                         \
  LG(4);                                                                      \
  MFMA16(af_a, bf_a, 0);                                                      \
  BAR();                                                                      \
  /* ph2 | issue af_a,bf_b<-ph3 */                                            \
  stage_unit(B_, col0, (KB) + 96, Lraw + 65536 + 49152, tid);                 \
  DSA(af_a, 0, 0, 1); DSB(bf_b, 0, 1);                                        \
  LG(8);                                                                      \
  MFMA16(af_b, bf_a, 1);                                                      \
  BAR();                                                                      \
  /* ph3 | issue af_b<-ph4 */                                                 \
  VM(4);                                                                      \
  if (PF) stage_unit(A_, row0, (KB) + 128, Lraw + 0, tid);                    \
  DSA(af_b, 0, 1, 1);                                                         \
  LG(4);                                                                      \
  MFMA16(af_a, bf_b, 0);                                                      \
  BAR();                                                                      \
  /* ph4 | issue af_a,bf_a<-ph5 (buf1) */                                     \
  if (PF) stage_unit(B_, col0, (KB) + 128, Lraw + 32768, tid);                \
  DSA(af_a, 1, 0, 0); DSB(bf_a, 1, 0);                                        \
  LG(8);                                                                      \
  MFMA16(af_b, bf_b, 1);                                                      \
  BAR();                                                                      \
  /* ph5 | issue af_b<-ph6 */                                                 \
  if (PF) { VM(4); } else { VM(0); }                                          \
  if (PF) stage_unit(A_, row0, (KB) + 160, Lraw + 16384, tid);                \
  DSA(af_b, 1, 1, 0);                                                         \
  LG(4);                                                                      \
  MFMA16(af_a, bf_a, 0);                                                      \
  BAR();                                                                      \
  /* ph6 | issue af_a,bf_b<-ph7 */                                            \
  if (PF) stage_unit(B_, col0, (KB) + 160, Lraw + 49152, tid);                \
  DSA(af_a, 1, 0, 1); DSB(bf_b, 1, 1);                                        \
  LG(8);                                                                      \
  MFMA16(af_b, bf_a, 1);                                                      \
  BAR();                                                                      \
  /* ph7 | issue af_b<-ph8 */                                                 \
  if (PF) { VM(4); }                                                          \
  if (PF) stage_unit(A_, row0, (KB) + 192, Lraw + 65536, tid);                \
  DSA(af_b, 1, 1, 1);                                                         \
  LG(4);                                                                      \
  MFMA16(af_a, bf_b, 0);                                                      \
  BAR();                                                                      \
  /* ph8 | issue af_a,bf_a<-next ph1 (buf0) */                                \
  if (PF) stage_unit(B_, col0, (KB) + 192, Lraw + 98304, tid);                \
  if (PF) { DSA(af_a, 0, 0, 0); DSB(bf_a, 0, 0); LG(8); } else { LG(0); }     \
  MFMA16(af_b, bf_b, 1);                                                      \
  if (PF) BAR();

__device__ __forceinline__ void gemm256_core(const bf16* __restrict__ A_,
                                             const bf16* __restrict__ B_,
                                             int row0, int col0,
                                             char* Lraw, f32x4 (&acc)[8][4]) {
  const int tid = threadIdx.x;
  const int wave = tid >> 6, lane = tid & 63, l16 = lane & 15, quad = lane >> 4;
  const int wr = wave >> 2, wc = wave & 3;
  int aoff[2][4], boff[4];
  #pragma unroll
  for (int mh = 0; mh < 2; ++mh)
    #pragma unroll
    for (int i = 0; i < 4; ++i) {
      const int row = wr * 128 + mh * 64 + i * 16 + l16;
      aoff[mh][i] = row * 64 + ((quad ^ ((row >> 1) & 3)) << 4);
    }
  #pragma unroll
  for (int j = 0; j < 4; ++j) {
    const int row = wc * 64 + j * 16 + l16;
    boff[j] = row * 64 + ((quad ^ ((row >> 1) & 3)) << 4);
  }
  bf16x8 af_a[4], af_b[4], bf_a[4], bf_b[4];
  // prologue: tile0 (4 units) + tile1 kh0 (2 units)
  stage_unit(A_, row0, 0,  Lraw + 0,      tid);
  stage_unit(B_, col0, 0,  Lraw + 32768,  tid);
  stage_unit(A_, row0, 32, Lraw + 16384,  tid);
  stage_unit(B_, col0, 32, Lraw + 49152,  tid);
  stage_unit(A_, row0, 64, Lraw + 65536,  tid);
  stage_unit(B_, col0, 64, Lraw + 98304,  tid);
  VM(8);                                   // tile0-ks0 (A0,B0) landed
  BAR();
  DSA(af_a, 0, 0, 0);                      // ph1 operands
  DSB(bf_a, 0, 0);
  for (int t = 0; t < 7; ++t) {            // tiles 0..13
    const int KB = t * 128;
    GITER(1, KB)
  }
  GITER(0, 896)                            // tiles 14,15 (epilogue)
}

// ---- GEMM1: xb[16384,1024] @ wt^T -> kv[16384,2048] bf16, XCD-swizzled ----
__global__ __launch_bounds__(512, 2) void k_gemm1(const bf16* __restrict__ A,
                                                  const bf16* __restrict__ Bt,
                                                  bf16* __restrict__ kv) {
  __shared__ __align__(16) char Lraw[131072];
  const int f = blockIdx.x, xcd = f & 7, w = f >> 3;
  const int row0 = (xcd * 8 + (w >> 3)) << 8;    // 64 row tiles of 256
  const int col0 = (w & 7) << 8;                 // 8 col tiles of 256
  f32x4 acc[8][4] = {};
  gemm256_core(A, Bt, row0, col0, Lraw, acc);
  const int tid = threadIdx.x;
  const int wave = tid >> 6, lane = tid & 63, l16 = lane & 15, quad = lane >> 4;
  const int wr = wave >> 2, wc = wave & 3;
  #pragma unroll
  for (int ai = 0; ai < 8; ++ai) {
    const int gm0 = row0 + wr * 128 + ai * 16 + quad * 4;
    #pragma unroll
    for (int j = 0; j < 4; ++j) {
      const int gc = col0 + wc * 64 + j * 16 + l16;
      #pragma unroll
      for (int r = 0; r < 4; ++r)
        kv[(size_t)(gm0 + r) * 2048 + gc] = (bf16)acc[ai][j][r];
    }
  }
}

// ---- ctx[b,h,d,e] = sum_{n unmasked} exp(k[n,hd]) * v[n,he]; sumexp folded -
__global__ __launch_bounds__(256) void k_ctx(const bf16* __restrict__ kv,
                                             const int* __restrict__ mask,
                                             float* __restrict__ sumexp,
                                             float* __restrict__ ctx) {
  __shared__ float Lk[64][68];
  __shared__ float Lv[64][68];
  __shared__ float Sst[64][33];
  const int blk = blockIdx.x, tid = threadIdx.x;
  const int wave = tid >> 6, lane = tid & 63;
  const int ns = blk & 7, h = (blk >> 3) & 15, b = blk >> 7;
  const int d0 = (lane & 7) * 8, e0 = (lane >> 3) * 8;
  const int g = tid & 7;                 // col-group, constant per thread
  float acc[8][8] = {};
  float sum8[8] = {};
  const int nbase = ns * 512;
  for (int ch = 0; ch < 8; ++ch) {
    const int n0 = nbase + ch * 64;
    __syncthreads();
    #pragma unroll
    for (int it = 0; it < 2; ++it) {               // k: exp, sum pre-mask, mask
      const int idx = it * 256 + tid;
      const int row = idx >> 3;
      const int gn = b * 4096 + n0 + row;
      const float m = mask[gn] ? 0.f : 1.f;
      bf16x8 t8 = *(const bf16x8*)(kv + (size_t)gn * 2048 + h * 64 + g * 8);
      float e[8];
      #pragma unroll
      for (int j = 0; j < 8; j++) { e[j] = __expf((float)t8[j]); sum8[j] += e[j]; }
      f32x4 lo, hi;
      lo[0] = e[0] * m; lo[1] = e[1] * m; lo[2] = e[2] * m; lo[3] = e[3] * m;
      hi[0] = e[4] * m; hi[1] = e[5] * m; hi[2] = e[6] * m; hi[3] = e[7] * m;
      *(f32x4*)&Lk[row][g * 8] = lo;
      *(f32x4*)&Lk[row][g * 8 + 4] = hi;
    }
    #pragma unroll
    for (int it = 0; it < 2; ++it) {               // v: plain convert
      const int idx = it * 256 + tid;
      const int row = idx >> 3;
      const int gn = b * 4096 + n0 + row;
      bf16x8 t8 = *(const bf16x8*)(kv + (size_t)gn * 2048 + 1024 + h * 64 + g * 8);
      f32x4 lo, hi;
      lo[0] = (float)t8[0]; lo[1] = (float)t8[1]; lo[2] = (float)t8[2]; lo[3] = (float)t8[3];
      hi[0] = (float)t8[4]; hi[1] = (float)t8[5]; hi[2] = (float)t8[6]; hi[3] = (float)t8[7];
      *(f32x4*)&Lv[row][g * 8] = lo;
      *(f32x4*)&Lv[row][g * 8 + 4] = hi;
    }
    __syncthreads();
    #pragma unroll 4
    for (int t = 0; t < 16; t++) {
      const int n = (wave << 4) + t;
      f32x4 ka = *(const f32x4*)&Lk[n][d0];
      f32x4 kb = *(const f32x4*)&Lk[n][d0 + 4];
      f32x4 va = *(const f32x4*)&Lv[n][e0];
      f32x4 vb = *(const f32x4*)&Lv[n][e0 + 4];
      float kk[8] = {ka[0], ka[1], ka[2], ka[3], kb[0], kb[1], kb[2], kb[3]};
      float vv[8] = {va[0], va[1], va[2], va[3], vb[0], vb[1], vb[2], vb[3]};
      #pragma unroll
      for (int a = 0; a < 8; a++)
        #pragma unroll
        for (int c = 0; c < 8; c++) acc[a][c] += kk[a] * vv[c];
    }
  }
  __syncthreads();
  float* r0 = &Lk[0][0];                           // reuse, stride 64
  float* r1 = &Lv[0][0];
  if (wave < 2) {
    float* r = wave ? r1 : r0;
    #pragma unroll
    for (int a = 0; a < 8; a++)
      #pragma unroll
      for (int c = 0; c < 8; c++) r[(d0 + a) * 64 + e0 + c] = acc[a][c];
  }
  {  // sumexp partials: Sst[col][rowgrp]
    const int rg = tid >> 3;
    #pragma unroll
    for (int j = 0; j < 8; j++) Sst[g * 8 + j][rg] = sum8[j];
  }
  __syncthreads();
  if (wave >= 2) {
    float* r = (wave == 3) ? r1 : r0;
    #pragma unroll
    for (int a = 0; a < 8; a++)
      #pragma unroll
      for (int c = 0; c < 8; c++) r[(d0 + a) * 64 + e0 + c] += acc[a][c];
  } else if (tid < 64) {                           // reduce sumexp col
    float s = 0.f;
    #pragma unroll 8
    for (int rg = 0; rg < 32; rg++) s += Sst[tid][rg];
    atomicAdd(&sumexp[b * 1024 + h * 64 + tid], s);
  }
  __syncthreads();
  float* cbase = ctx + ((size_t)(b * 16 + h) << 12);
  for (int i = tid; i < 4096; i += 256) atomicAdd(cbase + i, r0[i] + r1[i]);
}

// ---- M2t[b][j][h*64+d] = (1/sumexp[b,hd]) * sum_e ctx[b,h,d,e]*Wout[he][j] -
__global__ __launch_bounds__(256) void k_m2(const float* __restrict__ ctx,
                                            const float* __restrict__ sumexp,
                                            const float* __restrict__ Wout,
                                            bf16* __restrict__ M2t) {
  __shared__ float Lc[64][64];
  __shared__ float Linv[64];
  const int b = blockIdx.z, h = blockIdx.y, jt = blockIdx.x;
  const int tid = threadIdx.x, dg = tid >> 6, jl = tid & 63;
  const float* cbase = ctx + ((size_t)(b * 16 + h) << 12);
  for (int i = tid; i < 4096; i += 256) (&Lc[0][0])[i] = cbase[i];
  if (tid < 64) Linv[tid] = 1.f / sumexp[b * 1024 + h * 64 + tid];
  __syncthreads();
  float acc[4][16] = {};
  const int j0 = jt * 256 + jl;
  for (int e = 0; e < 64; e++) {
    const float* wrow = Wout + (size_t)(h * 64 + e) * 1024 + j0;
    float w0 = wrow[0], w1 = wrow[64], w2 = wrow[128], w3 = wrow[192];
    #pragma unroll
    for (int dd = 0; dd < 16; dd++) {
      float c = Lc[dg * 16 + dd][e];  // wave-uniform -> LDS broadcast
      acc[0][dd] += c * w0; acc[1][dd] += c * w1;
      acc[2][dd] += c * w2; acc[3][dd] += c * w3;
    }
  }
  #pragma unroll
  for (int jj = 0; jj < 4; jj++) {
    const size_t jrow = ((size_t)b << 20) + (size_t)(jt * 256 + jl + jj * 64) * 1024 + h * 64 + dg * 16;
    #pragma unroll
    for (int dd = 0; dd < 16; dd++)
      M2t[jrow + dd] = (bf16)(acc[jj][dd] * Linv[dg * 16 + dd]);
  }
}

// ---- M3t[b] = M2t[b] @ wqs^T, bf16 out (m97 structure, M=N=K=1024) --------
__global__ __launch_bounds__(256) void k_m3(const bf16* __restrict__ M2t,
                                            const bf16* __restrict__ wqs,
                                            bf16* __restrict__ M3t) {
  __shared__ __align__(16) bf16 As[128 * 32];
  __shared__ __align__(16) bf16 Bs[128 * 32];
  const int tid = threadIdx.x;
  const int wave = tid >> 6, lane = tid & 63, l16 = lane & 15, quad = lane >> 4;
  const int wm = (wave >> 1) << 6, wn = (wave & 1) << 6;
  const int row0 = blockIdx.y << 7, col0 = blockIdx.x << 7;
  const bf16* A  = M2t + ((size_t)blockIdx.z << 20);
  bf16*       C  = M3t + ((size_t)blockIdx.z << 20);
  f32x4 acc[4][4] = {};
  for (int kt = 0; kt < 1024; kt += 32) {
    #pragma unroll
    for (int it = 0; it < 2; ++it) {
      const int cb = (wave * 2 + it) * 64;
      const int c = cb + lane;
      const int m = c >> 2, k8 = (c & 3) * 8;
      g2l16(A   + (size_t)(row0 + m) * 1024 + kt + k8, As + cb * 8);
      g2l16(wqs + (size_t)(col0 + m) * 1024 + kt + k8, Bs + cb * 8);
    }
    __syncthreads();
    bf16x8 af[4], bfr[4];
    #pragma unroll
    for (int i = 0; i < 4; i++) af[i]  = *(const bf16x8*)(As + (wm + i * 16 + l16) * 32 + quad * 8);
    #pragma unroll
    for (int j = 0; j < 4; j++) bfr[j] = *(const bf16x8*)(Bs + (wn + j * 16 + l16) * 32 + quad * 8);
    #pragma unroll
    for (int i = 0; i < 4; i++)
      #pragma unroll
      for (int j = 0; j < 4; j++)
        acc[i][j] = __builtin_amdgcn_mfma_f32_16x16x32_bf16(af[i], bfr[j], acc[i][j], 0, 0, 0);
    __syncthreads();
  }
  #pragma unroll
  for (int i = 0; i < 4; i++) {
    const int gm0 = row0 + wm + i * 16 + quad * 4;
    #pragma unroll
    for (int j = 0; j < 4; j++) {
      const int gc = col0 + wn + j * 16 + l16;
      #pragma unroll
      for (int r = 0; r < 4; r++)
        C[(size_t)(gm0 + r) * 1024 + gc] = (bf16)acc[i][j][r];
    }
  }
}

// ---- GEMM2: out[b] = xb[b] @ M3t[b]^T + b_out, fp32, XCD-swizzled ---------
__global__ __launch_bounds__(512, 2) void k_gemm2(const bf16* __restrict__ A,
                                                  const bf16* __restrict__ M3t,
                                                  const float* __restrict__ bias,
                                                  float* __restrict__ out) {
  __shared__ __align__(16) char Lraw[131072];
  const int f = blockIdx.x, xcd = f & 7, w = f >> 3;
  const int row0 = (xcd * 8 + (w >> 2)) << 8;    // 64 row tiles of 256
  const int col0 = (w & 3) << 8;                 // 4 col tiles of 256
  const bf16* Bt = M3t + ((size_t)(row0 >> 12) << 20);   // per-batch B
  f32x4 acc[8][4] = {};
  gemm256_core(A, Bt, row0, col0, Lraw, acc);
  const int tid = threadIdx.x;
  const int wave = tid >> 6, lane = tid & 63, l16 = lane & 15, quad = lane >> 4;
  const int wr = wave >> 2, wc = wave & 3;
  float bj[4];
  #pragma unroll
  for (int j = 0; j < 4; j++) bj[j] = bias[col0 + wc * 64 + j * 16 + l16];
  #pragma unroll
  for (int ai = 0; ai < 8; ++ai) {
    const int gm0 = row0 + wr * 128 + ai * 16 + quad * 4;
    #pragma unroll
    for (int j = 0; j < 4; ++j) {
      const int gc = col0 + wc * 64 + j * 16 + l16;
      #pragma unroll
      for (int r = 0; r < 4; ++r)
        out[(size_t)(gm0 + r) * 1024 + gc] = acc[ai][j][r] + bj[j];
    }
  }
}

// ---------------------------------------------------------------------------
extern "C" void kernel_launch(void* const* d_in, const int* in_sizes, int n_in,
                              void* d_out, int out_size, void* d_ws, size_t ws_size,
                              hipStream_t stream) {
  const float* x    = (const float*)d_in[0];
  const int*   mask = (const int*)d_in[1];
  const float* Wqkv = (const float*)d_in[2];
  const float* Wout = (const float*)d_in[3];
  const float* bout = (const float*)d_in[4];
  float* out = (float*)d_out;
  char* ws = (char*)d_ws;
  bf16*  xb     = (bf16*)(ws);                   // 16384*1024 bf16 (32 MB)
  bf16*  wt     = (bf16*)(ws + 33554432);        // 2048*1024 bf16  (4 MB)
  bf16*  wqs    = (bf16*)(ws + 37748736);        // 1024*1024 bf16  (2 MB)
  bf16*  kv     = (bf16*)(ws + 39845888);        // 16384*2048 bf16 (64 MB)
  float* sumexp = (float*)(ws + 106954752);      // 4096 f32 (16 KB)
  float* ctx    = (float*)(ws + 106971136);      // 4*16*64*64 f32 (1 MB)
  bf16*  m2t    = (bf16*)(ws + 108019712);       // 4*1024*1024 bf16 (8 MB)
  bf16*  m3t    = (bf16*)(ws + 116408320);       // 4*1024*1024 bf16 (8 MB)

  hipMemsetAsync(sumexp, 0, 16384 + 1048576, stream);   // sumexp + ctx
  k_cvt  <<<16384, 256, 0, stream>>>(x, xb, 4194304);
  k_trans<<<dim3(64, 32), 256, 0, stream>>>(Wqkv, wt);
  k_wq   <<<1024, 256, 0, stream>>>(Wqkv, wqs);
  k_gemm1<<<512, 512, 0, stream>>>(xb, wt, kv);
  k_ctx  <<<512, 256, 0, stream>>>(kv, mask, sumexp, ctx);
  k_m2   <<<dim3(4, 16, 4), 256, 0, stream>>>(ctx, sumexp, Wout, m2t);
  k_m3   <<<dim3(8, 8, 4), 256, 0, stream>>>(m2t, wqs, m3t);
  k_gemm2<<<256, 512, 0, stream>>>(xb, m3t, bout, out);
}

// Round 4
// 320.947 us; speedup vs baseline: 1.0327x; 1.0327x over previous
//
#include <hip/hip_runtime.h>
#include <math.h>

// ---------------------------------------------------------------------------
// LinearAttention, folded. Plain dispatches only (no cooperative launch).
//   cvt/trans/wq: x->bf16, Wkv^T->bf16, Wq*scale->bf16
//   gemm1: kv = x @ Wkv  (256^2 8-phase MFMA, m201-faithful, XCD-swizzled)
//   ctx:   ctx[b,h,d,e] = sum_n_unmasked exp(k)*v ; sumexp folded (pre-mask)
//   m2:    M2t[b] = (blockdiag(ctx)/sumexp @ Wout)^T  bf16
//   m3:    M3t[b] = M2t[b] @ (s*Wq)^T                 bf16  (m97 structure)
//   gemm2: out = x @ M3t^T + b_out (fp32, same 8-phase core, XCD-swizzled)
// B=4 T=4096 DIM=1024 H=16 Dh=64.
//
// Round-4: m201-faithful phase schedule (single frag bank):
//   phase = { ds_read this phase's frags (8 or 4 b128) -> stage 1 unit ->
//             [VM(8) even phases, AFTER stage, BEFORE bar1 -> wait off the
//              read path; bar1 publishes] -> bar1 -> lgkmcnt(0)+SGB(0) ->
//             setprio(1) 16xMFMA setprio(0) -> bar2 }.
//   Staging remapped for 6-phase issue->first-read distance:
//     ph1 buf1.A-ks1(t2I+1), ph2 buf1.B-ks1, ph3 buf0.A-ks0(t2I+2),
//     ph4 buf0.B-ks0, ph5 buf0.A-ks1, ph6 buf0.B-ks1, ph7 buf1.A-ks0(t2I+3),
//     ph8 buf1.B-ks0.  VM(8) = 4 units in flight.
//   Epilogue iter: ph1/2 still stage (tile15-ks1); ph3-8 none;
//     VM(8)@ph2, VM(4)@ph4, VM(0)@ph6 keep every read forced+published.
//   WAR: every stage target's last read lgkm-completes >=2 barriers earlier.
// m3/ctx/m2/preps = round-0 verified bodies.
// ---------------------------------------------------------------------------

typedef __bf16 bf16;
typedef __attribute__((ext_vector_type(4))) float f32x4;
typedef __attribute__((ext_vector_type(8))) __bf16 bf16x8;
typedef __attribute__((ext_vector_type(4))) __bf16 bf16x4;

#define SCALE_ 0.125f   // 64^-0.5

__device__ __forceinline__ void g2l16(const void* g, void* l) {
  __builtin_amdgcn_global_load_lds((const __attribute__((address_space(1))) void*)g,
                                   (__attribute__((address_space(3))) void*)l, 16, 0, 0);
}

// ---- x (fp32) -> bf16, vectorized (round-2 verified) ----------------------
__global__ __launch_bounds__(256) void k_cvt(const float* __restrict__ in,
                                             bf16* __restrict__ out, int n4) {
  int i = blockIdx.x * 256 + threadIdx.x;
  if (i >= n4) return;
  f32x4 v = ((const f32x4*)in)[i];
  bf16x4 o;
  o[0] = (bf16)v[0]; o[1] = (bf16)v[1]; o[2] = (bf16)v[2]; o[3] = (bf16)v[3];
  ((bf16x4*)out)[i] = o;
}

// ---- W_qkv[:,1024:3072] fp32 -> wt [2048][1024] bf16 (round-2 verified) ---
__global__ __launch_bounds__(256) void k_trans(const float* __restrict__ W,
                                               bf16* __restrict__ Wt) {
  __shared__ float t[32][33];
  int n0 = blockIdx.x * 32, k0 = blockIdx.y * 32;
  int tx = threadIdx.x & 31, ty = threadIdx.x >> 5;
  #pragma unroll
  for (int s = 0; s < 4; s++) {
    int k = ty + s * 8;
    t[k][tx] = W[(size_t)(k0 + k) * 3072 + 1024 + n0 + tx];
  }
  __syncthreads();
  #pragma unroll
  for (int s = 0; s < 4; s++) {
    int n = ty + s * 8;
    Wt[(size_t)(n0 + n) * 1024 + k0 + tx] = (bf16)t[tx][n];
  }
}

// ---- wqs[i][d] = scale * Wqkv[i][d] (round-2 verified) --------------------
__global__ __launch_bounds__(256) void k_wq(const float* __restrict__ W,
                                            bf16* __restrict__ wqs) {
  int idx = blockIdx.x * 256 + threadIdx.x;     // 1024*256 total
  int i = idx >> 8, d4 = idx & 255;
  f32x4 v = *(const f32x4*)(W + (size_t)i * 3072 + d4 * 4);
  bf16x4 o;
  o[0] = (bf16)(v[0] * SCALE_); o[1] = (bf16)(v[1] * SCALE_);
  o[2] = (bf16)(v[2] * SCALE_); o[3] = (bf16)(v[3] * SCALE_);
  *(bf16x4*)(wqs + (size_t)i * 1024 + d4 * 4) = o;
}

// ===========================================================================
// 256x256 / BK=64 / 8-wave / 8-phase GEMM core, m201-faithful (K = 1024)
// LDS map (bytes): buf d at d*65536; within buf: A-ks0 +0, A-ks1 +16384,
//                  B-ks0 +32768, B-ks1 +49152. Unit = 16KB K-half.
// ===========================================================================

__device__ __forceinline__ void stage_unit(const bf16* __restrict__ G, int base_row,
                                           int kcol, void* ldsBase, int tid) {
  #pragma unroll
  for (int r = 0; r < 2; ++r) {
    const int d  = tid * 16 + r * 8192;              // linear byte in unit
    const int lb = d ^ (((d >> 7) & 3) << 4);        // logical byte (involution)
    g2l16(G + (size_t)(base_row + (lb >> 6)) * 1024 + kcol + ((lb & 63) >> 1),
          (char*)ldsBase + d);
  }
}

#define VM(n) asm volatile("s_waitcnt vmcnt(" #n ")" ::: "memory")

// phase: ds_read frags -> stage/VM (variadic) -> bar1 -> lgkm(0)+SGB ->
//        setprio(1) MFMA x16 setprio(0) -> bar2
#define PH(DB, MH, KS, LOADB, ...)                                            \
  {                                                                           \
    const char* Ab_ = Lraw + (DB) * 65536 + (KS) * 16384;                     \
    _Pragma("unroll") for (int i_ = 0; i_ < 4; ++i_)                          \
      af[i_] = *(const bf16x8*)(Ab_ + aoff[MH][i_]);                          \
    if (LOADB) {                                                              \
      _Pragma("unroll") for (int j_ = 0; j_ < 4; ++j_)                        \
        bfr[j_] = *(const bf16x8*)(Ab_ + 32768 + boff[j_]);                   \
    }                                                                         \
    __VA_ARGS__;                                                              \
    __builtin_amdgcn_s_barrier();                                             \
    asm volatile("s_waitcnt lgkmcnt(0)" ::: "memory");                        \
    __builtin_amdgcn_sched_barrier(0);                                        \
    __builtin_amdgcn_s_setprio(1);                                            \
    _Pragma("unroll") for (int i_ = 0; i_ < 4; ++i_)                          \
      _Pragma("unroll") for (int j_ = 0; j_ < 4; ++j_)                        \
        acc[(MH) * 4 + i_][j_] = __builtin_amdgcn_mfma_f32_16x16x32_bf16(     \
            af[i_], bfr[j_], acc[(MH) * 4 + i_][j_], 0, 0, 0);                \
    __builtin_amdgcn_s_setprio(0);                                            \
    __builtin_amdgcn_s_barrier();                                             \
  }

__device__ __forceinline__ void gemm256_core(const bf16* __restrict__ A_,
                                             const bf16* __restrict__ B_,
                                             int row0, int col0,
                                             char* Lraw, f32x4 (&acc)[8][4]) {
  const int tid = threadIdx.x;
  const int wave = tid >> 6, lane = tid & 63, l16 = lane & 15, quad = lane >> 4;
  const int wr = wave >> 2, wc = wave & 3;
  int aoff[2][4], boff[4];
  #pragma unroll
  for (int mh = 0; mh < 2; ++mh)
    #pragma unroll
    for (int i = 0; i < 4; ++i) {
      const int row = wr * 128 + mh * 64 + i * 16 + l16;
      aoff[mh][i] = row * 64 + ((quad ^ ((row >> 1) & 3)) << 4);
    }
  #pragma unroll
  for (int j = 0; j < 4; ++j) {
    const int row = wc * 64 + j * 16 + l16;
    boff[j] = row * 64 + ((quad ^ ((row >> 1) & 3)) << 4);
  }
  bf16x8 af[4], bfr[4];
  // prologue: tile0 (4 units) + tile1 ks0 (2 units); VM(8) forces tile0-ks0
  stage_unit(A_, row0, 0,  Lraw + 0,      tid);
  stage_unit(B_, col0, 0,  Lraw + 32768,  tid);
  stage_unit(A_, row0, 32, Lraw + 16384,  tid);
  stage_unit(B_, col0, 32, Lraw + 49152,  tid);
  stage_unit(A_, row0, 64, Lraw + 65536,  tid);
  stage_unit(B_, col0, 64, Lraw + 98304,  tid);
  VM(8);
  __builtin_amdgcn_s_barrier();
  for (int I = 0; I < 7; ++I) {            // tiles 0..13
    const int KB = I * 128;
    PH(0, 0, 0, 1, stage_unit(A_, row0, KB + 96,  Lraw + 81920,  tid);        )
    PH(0, 1, 0, 0, stage_unit(B_, col0, KB + 96,  Lraw + 114688, tid); VM(8); )
    PH(0, 0, 1, 1, stage_unit(A_, row0, KB + 128, Lraw + 0,      tid);        )
    PH(0, 1, 1, 0, stage_unit(B_, col0, KB + 128, Lraw + 32768,  tid); VM(8); )
    PH(1, 0, 0, 1, stage_unit(A_, row0, KB + 160, Lraw + 16384,  tid);        )
    PH(1, 1, 0, 0, stage_unit(B_, col0, KB + 160, Lraw + 49152,  tid); VM(8); )
    PH(1, 0, 1, 1, stage_unit(A_, row0, KB + 192, Lraw + 65536,  tid);        )
    PH(1, 1, 1, 0, stage_unit(B_, col0, KB + 192, Lraw + 98304,  tid); VM(8); )
  }
  // epilogue: tiles 14,15 ; prefetch stops, drains VM(8)->VM(4)->VM(0)
  PH(0, 0, 0, 1, stage_unit(A_, row0, 992, Lraw + 81920,  tid);        )
  PH(0, 1, 0, 0, stage_unit(B_, col0, 992, Lraw + 114688, tid); VM(8); )
  PH(0, 0, 1, 1,                                                       )
  PH(0, 1, 1, 0, VM(4);                                                )
  PH(1, 0, 0, 1,                                                       )
  PH(1, 1, 0, 0, VM(0);                                                )
  PH(1, 0, 1, 1,                                                       )
  PH(1, 1, 1, 0,                                                       )
}

// ---- GEMM1: xb[16384,1024] @ wt^T -> kv[16384,2048] bf16, XCD-swizzled ----
__global__ __launch_bounds__(512, 2) void k_gemm1(const bf16* __restrict__ A,
                                                  const bf16* __restrict__ Bt,
                                                  bf16* __restrict__ kv) {
  __shared__ __align__(16) char Lraw[131072];
  const int f = blockIdx.x, xcd = f & 7, w = f >> 3;
  const int row0 = (xcd * 8 + (w >> 3)) << 8;    // 64 row tiles of 256
  const int col0 = (w & 7) << 8;                 // 8 col tiles of 256
  f32x4 acc[8][4] = {};
  gemm256_core(A, Bt, row0, col0, Lraw, acc);
  const int tid = threadIdx.x;
  const int wave = tid >> 6, lane = tid & 63, l16 = lane & 15, quad = lane >> 4;
  const int wr = wave >> 2, wc = wave & 3;
  #pragma unroll
  for (int ai = 0; ai < 8; ++ai) {
    const int gm0 = row0 + wr * 128 + ai * 16 + quad * 4;
    #pragma unroll
    for (int j = 0; j < 4; ++j) {
      const int gc = col0 + wc * 64 + j * 16 + l16;
      #pragma unroll
      for (int r = 0; r < 4; ++r)
        kv[(size_t)(gm0 + r) * 2048 + gc] = (bf16)acc[ai][j][r];
    }
  }
}

// ---- ctx[b,h,d,e] = sum_{n unmasked} exp(k[n,hd]) * v[n,he]; sumexp folded -
__global__ __launch_bounds__(256) void k_ctx(const bf16* __restrict__ kv,
                                             const int* __restrict__ mask,
                                             float* __restrict__ sumexp,
                                             float* __restrict__ ctx) {
  __shared__ float Lk[64][68];
  __shared__ float Lv[64][68];
  __shared__ float Sst[64][33];
  const int blk = blockIdx.x, tid = threadIdx.x;
  const int wave = tid >> 6, lane = tid & 63;
  const int ns = blk & 7, h = (blk >> 3) & 15, b = blk >> 7;
  const int d0 = (lane & 7) * 8, e0 = (lane >> 3) * 8;
  const int g = tid & 7;                 // col-group, constant per thread
  float acc[8][8] = {};
  float sum8[8] = {};
  const int nbase = ns * 512;
  for (int ch = 0; ch < 8; ++ch) {
    const int n0 = nbase + ch * 64;
    __syncthreads();
    #pragma unroll
    for (int it = 0; it < 2; ++it) {               // k: exp, sum pre-mask, mask
      const int idx = it * 256 + tid;
      const int row = idx >> 3;
      const int gn = b * 4096 + n0 + row;
      const float m = mask[gn] ? 0.f : 1.f;
      bf16x8 t8 = *(const bf16x8*)(kv + (size_t)gn * 2048 + h * 64 + g * 8);
      float e[8];
      #pragma unroll
      for (int j = 0; j < 8; j++) { e[j] = __expf((float)t8[j]); sum8[j] += e[j]; }
      f32x4 lo, hi;
      lo[0] = e[0] * m; lo[1] = e[1] * m; lo[2] = e[2] * m; lo[3] = e[3] * m;
      hi[0] = e[4] * m; hi[1] = e[5] * m; hi[2] = e[6] * m; hi[3] = e[7] * m;
      *(f32x4*)&Lk[row][g * 8] = lo;
      *(f32x4*)&Lk[row][g * 8 + 4] = hi;
    }
    #pragma unroll
    for (int it = 0; it < 2; ++it) {               // v: plain convert
      const int idx = it * 256 + tid;
      const int row = idx >> 3;
      const int gn = b * 4096 + n0 + row;
      bf16x8 t8 = *(const bf16x8*)(kv + (size_t)gn * 2048 + 1024 + h * 64 + g * 8);
      f32x4 lo, hi;
      lo[0] = (float)t8[0]; lo[1] = (float)t8[1]; lo[2] = (float)t8[2]; lo[3] = (float)t8[3];
      hi[0] = (float)t8[4]; hi[1] = (float)t8[5]; hi[2] = (float)t8[6]; hi[3] = (float)t8[7];
      *(f32x4*)&Lv[row][g * 8] = lo;
      *(f32x4*)&Lv[row][g * 8 + 4] = hi;
    }
    __syncthreads();
    #pragma unroll 4
    for (int t = 0; t < 16; t++) {
      const int n = (wave << 4) + t;
      f32x4 ka = *(const f32x4*)&Lk[n][d0];
      f32x4 kb = *(const f32x4*)&Lk[n][d0 + 4];
      f32x4 va = *(const f32x4*)&Lv[n][e0];
      f32x4 vb = *(const f32x4*)&Lv[n][e0 + 4];
      float kk[8] = {ka[0], ka[1], ka[2], ka[3], kb[0], kb[1], kb[2], kb[3]};
      float vv[8] = {va[0], va[1], va[2], va[3], vb[0], vb[1], vb[2], vb[3]};
      #pragma unroll
      for (int a = 0; a < 8; a++)
        #pragma unroll
        for (int c = 0; c < 8; c++) acc[a][c] += kk[a] * vv[c];
    }
  }
  __syncthreads();
  float* r0 = &Lk[0][0];                           // reuse, stride 64
  float* r1 = &Lv[0][0];
  if (wave < 2) {
    float* r = wave ? r1 : r0;
    #pragma unroll
    for (int a = 0; a < 8; a++)
      #pragma unroll
      for (int c = 0; c < 8; c++) r[(d0 + a) * 64 + e0 + c] = acc[a][c];
  }
  {  // sumexp partials: Sst[col][rowgrp]
    const int rg = tid >> 3;
    #pragma unroll
    for (int j = 0; j < 8; j++) Sst[g * 8 + j][rg] = sum8[j];
  }
  __syncthreads();
  if (wave >= 2) {
    float* r = (wave == 3) ? r1 : r0;
    #pragma unroll
    for (int a = 0; a < 8; a++)
      #pragma unroll
      for (int c = 0; c < 8; c++) r[(d0 + a) * 64 + e0 + c] += acc[a][c];
  } else if (tid < 64) {                           // reduce sumexp col
    float s = 0.f;
    #pragma unroll 8
    for (int rg = 0; rg < 32; rg++) s += Sst[tid][rg];
    atomicAdd(&sumexp[b * 1024 + h * 64 + tid], s);
  }
  __syncthreads();
  float* cbase = ctx + ((size_t)(b * 16 + h) << 12);
  for (int i = tid; i < 4096; i += 256) atomicAdd(cbase + i, r0[i] + r1[i]);
}

// ---- M2t[b][j][h*64+d] = (1/sumexp[b,hd]) * sum_e ctx[b,h,d,e]*Wout[he][j] -
__global__ __launch_bounds__(256) void k_m2(const float* __restrict__ ctx,
                                            const float* __restrict__ sumexp,
                                            const float* __restrict__ Wout,
                                            bf16* __restrict__ M2t) {
  __shared__ float Lc[64][64];
  __shared__ float Linv[64];
  const int b = blockIdx.z, h = blockIdx.y, jt = blockIdx.x;
  const int tid = threadIdx.x, dg = tid >> 6, jl = tid & 63;
  const float* cbase = ctx + ((size_t)(b * 16 + h) << 12);
  for (int i = tid; i < 4096; i += 256) (&Lc[0][0])[i] = cbase[i];
  if (tid < 64) Linv[tid] = 1.f / sumexp[b * 1024 + h * 64 + tid];
  __syncthreads();
  float acc[4][16] = {};
  const int j0 = jt * 256 + jl;
  for (int e = 0; e < 64; e++) {
    const float* wrow = Wout + (size_t)(h * 64 + e) * 1024 + j0;
    float w0 = wrow[0], w1 = wrow[64], w2 = wrow[128], w3 = wrow[192];
    #pragma unroll
    for (int dd = 0; dd < 16; dd++) {
      float c = Lc[dg * 16 + dd][e];  // wave-uniform -> LDS broadcast
      acc[0][dd] += c * w0; acc[1][dd] += c * w1;
      acc[2][dd] += c * w2; acc[3][dd] += c * w3;
    }
  }
  #pragma unroll
  for (int jj = 0; jj < 4; jj++) {
    const size_t jrow = ((size_t)b << 20) + (size_t)(jt * 256 + jl + jj * 64) * 1024 + h * 64 + dg * 16;
    #pragma unroll
    for (int dd = 0; dd < 16; dd++)
      M2t[jrow + dd] = (bf16)(acc[jj][dd] * Linv[dg * 16 + dd]);
  }
}

// ---- M3t[b] = M2t[b] @ wqs^T, bf16 out (m97 structure, M=N=K=1024) --------
__global__ __launch_bounds__(256) void k_m3(const bf16* __restrict__ M2t,
                                            const bf16* __restrict__ wqs,
                                            bf16* __restrict__ M3t) {
  __shared__ __align__(16) bf16 As[128 * 32];
  __shared__ __align__(16) bf16 Bs[128 * 32];
  const int tid = threadIdx.x;
  const int wave = tid >> 6, lane = tid & 63, l16 = lane & 15, quad = lane >> 4;
  const int wm = (wave >> 1) << 6, wn = (wave & 1) << 6;
  const int row0 = blockIdx.y << 7, col0 = blockIdx.x << 7;
  const bf16* A  = M2t + ((size_t)blockIdx.z << 20);
  bf16*       C  = M3t + ((size_t)blockIdx.z << 20);
  f32x4 acc[4][4] = {};
  for (int kt = 0; kt < 1024; kt += 32) {
    #pragma unroll
    for (int it = 0; it < 2; ++it) {
      const int cb = (wave * 2 + it) * 64;
      const int c = cb + lane;
      const int m = c >> 2, k8 = (c & 3) * 8;
      g2l16(A   + (size_t)(row0 + m) * 1024 + kt + k8, As + cb * 8);
      g2l16(wqs + (size_t)(col0 + m) * 1024 + kt + k8, Bs + cb * 8);
    }
    __syncthreads();
    bf16x8 af[4], bfr[4];
    #pragma unroll
    for (int i = 0; i < 4; i++) af[i]  = *(const bf16x8*)(As + (wm + i * 16 + l16) * 32 + quad * 8);
    #pragma unroll
    for (int j = 0; j < 4; j++) bfr[j] = *(const bf16x8*)(Bs + (wn + j * 16 + l16) * 32 + quad * 8);
    #pragma unroll
    for (int i = 0; i < 4; i++)
      #pragma unroll
      for (int j = 0; j < 4; j++)
        acc[i][j] = __builtin_amdgcn_mfma_f32_16x16x32_bf16(af[i], bfr[j], acc[i][j], 0, 0, 0);
    __syncthreads();
  }
  #pragma unroll
  for (int i = 0; i < 4; i++) {
    const int gm0 = row0 + wm + i * 16 + quad * 4;
    #pragma unroll
    for (int j = 0; j < 4; j++) {
      const int gc = col0 + wn + j * 16 + l16;
      #pragma unroll
      for (int r = 0; r < 4; r++)
        C[(size_t)(gm0 + r) * 1024 + gc] = (bf16)acc[i][j][r];
    }
  }
}

// ---- GEMM2: out[b] = xb[b] @ M3t[b]^T + b_out, fp32, XCD-swizzled ---------
__global__ __launch_bounds__(512, 2) void k_gemm2(const bf16* __restrict__ A,
                                                  const bf16* __restrict__ M3t,
                                                  const float* __restrict__ bias,
                                                  float* __restrict__ out) {
  __shared__ __align__(16) char Lraw[131072];
  const int f = blockIdx.x, xcd = f & 7, w = f >> 3;
  const int row0 = (xcd * 8 + (w >> 2)) << 8;    // 64 row tiles of 256
  const int col0 = (w & 3) << 8;                 // 4 col tiles of 256
  const bf16* Bt = M3t + ((size_t)(row0 >> 12) << 20);   // per-batch B
  f32x4 acc[8][4] = {};
  gemm256_core(A, Bt, row0, col0, Lraw, acc);
  const int tid = threadIdx.x;
  const int wave = tid >> 6, lane = tid & 63, l16 = lane & 15, quad = lane >> 4;
  const int wr = wave >> 2, wc = wave & 3;
  float bj[4];
  #pragma unroll
  for (int j = 0; j < 4; j++) bj[j] = bias[col0 + wc * 64 + j * 16 + l16];
  #pragma unroll
  for (int ai = 0; ai < 8; ++ai) {
    const int gm0 = row0 + wr * 128 + ai * 16 + quad * 4;
    #pragma unroll
    for (int j = 0; j < 4; ++j) {
      const int gc = col0 + wc * 64 + j * 16 + l16;
      #pragma unroll
      for (int r = 0; r < 4; ++r)
        out[(size_t)(gm0 + r) * 1024 + gc] = acc[ai][j][r] + bj[j];
    }
  }
}

// ---------------------------------------------------------------------------
extern "C" void kernel_launch(void* const* d_in, const int* in_sizes, int n_in,
                              void* d_out, int out_size, void* d_ws, size_t ws_size,
                              hipStream_t stream) {
  const float* x    = (const float*)d_in[0];
  const int*   mask = (const int*)d_in[1];
  const float* Wqkv = (const float*)d_in[2];
  const float* Wout = (const float*)d_in[3];
  const float* bout = (const float*)d_in[4];
  float* out = (float*)d_out;
  char* ws = (char*)d_ws;
  bf16*  xb     = (bf16*)(ws);                   // 16384*1024 bf16 (32 MB)
  bf16*  wt     = (bf16*)(ws + 33554432);        // 2048*1024 bf16  (4 MB)
  bf16*  wqs    = (bf16*)(ws + 37748736);        // 1024*1024 bf16  (2 MB)
  bf16*  kv     = (bf16*)(ws + 39845888);        // 16384*2048 bf16 (64 MB)
  float* sumexp = (float*)(ws + 106954752);      // 4096 f32 (16 KB)
  float* ctx    = (float*)(ws + 106971136);      // 4*16*64*64 f32 (1 MB)
  bf16*  m2t    = (bf16*)(ws + 108019712);       // 4*1024*1024 bf16 (8 MB)
  bf16*  m3t    = (bf16*)(ws + 116408320);       // 4*1024*1024 bf16 (8 MB)

  hipMemsetAsync(sumexp, 0, 16384 + 1048576, stream);   // sumexp + ctx
  k_cvt  <<<16384, 256, 0, stream>>>(x, xb, 4194304);
  k_trans<<<dim3(64, 32), 256, 0, stream>>>(Wqkv, wt);
  k_wq   <<<1024, 256, 0, stream>>>(Wqkv, wqs);
  k_gemm1<<<512, 512, 0, stream>>>(xb, wt, kv);
  k_ctx  <<<512, 256, 0, stream>>>(kv, mask, sumexp, ctx);
  k_m2   <<<dim3(4, 16, 4), 256, 0, stream>>>(ctx, sumexp, Wout, m2t);
  k_m3   <<<dim3(8, 8, 4), 256, 0, stream>>>(m2t, wqs, m3t);
  k_gemm2<<<256, 512, 0, stream>>>(xb, m3t, bout, out);
}